// Round 1
// baseline (279.741 us; speedup 1.0000x reference)
//
#include <hip/hip_runtime.h>
#include <math.h>

// Problem constants (from reference): feature_map [16,64,224,224], points [16,1024,2]
#define BB   16
#define HH   224
#define WW   224
#define NPTS 1024
#define KS   23      // int(224*0.1)=22 -> +1 = 23
#define HALF 11
#define SIGMA2_2 18.0f  // 2*sigma^2, sigma=3

// Compute the L1-normalized 1D gaussian weights (matches reference:
// exp(-(i-c)^2/(2*sigma^2)) / sum). 23 expf per thread — negligible.
__device__ __forceinline__ void gauss_weights(float* w) {
    float s = 0.0f;
#pragma unroll
    for (int t = 0; t < KS; ++t) {
        float ax = (float)(t - HALF);
        float v = __expf(-(ax * ax) / SIGMA2_2);
        w[t] = v;
        s += v;
    }
    float inv = 1.0f / s;
#pragma unroll
    for (int t = 0; t < KS; ++t) w[t] *= inv;
}

// Step 2: scatter point counts into [B,H,W] grid (grid pre-zeroed by memset).
__global__ void scatter_counts(const float* __restrict__ pts, float* __restrict__ cnt) {
    int idx = blockIdx.x * blockDim.x + threadIdx.x;
    if (idx >= BB * NPTS) return;
    int b = idx / NPTS;
    float px = pts[2 * idx + 0];
    float py = pts[2 * idx + 1];
    int x = (int)(px * (float)WW);  // trunc of nonneg == astype(int32)
    int y = (int)(py * (float)HH);
    // points are uniform [0,1) so always in bounds; guard only vs OOB crash
    if ((unsigned)x >= WW || (unsigned)y >= HH) return;
    atomicAdd(&cnt[(b * HH + y) * WW + x], 1.0f);
}

// Step 3: horizontal 23-tap conv with zero padding. cnt[B,H,W] -> tmp[B,H,W]
__global__ void hconv(const float* __restrict__ cnt, float* __restrict__ tmp) {
    int idx = blockIdx.x * blockDim.x + threadIdx.x;
    if (idx >= BB * HH * WW) return;
    float w[KS];
    gauss_weights(w);
    int j = idx % WW;
    int rowbase = idx - j;
    int lo = j - HALF; if (lo < 0) lo = 0;
    int hi = j + HALF; if (hi > WW - 1) hi = WW - 1;
    float acc = 0.0f;
    for (int x = lo; x <= hi; ++x)
        acc += cnt[rowbase + x] * w[x - j + HALF];
    tmp[idx] = acc;
}

// Step 4: vertical 23-tap conv with zero padding. tmp[B,H,W] -> out[B,H,W]
__global__ void vconv(const float* __restrict__ tmp, float* __restrict__ out) {
    int idx = blockIdx.x * blockDim.x + threadIdx.x;
    if (idx >= BB * HH * WW) return;
    float w[KS];
    gauss_weights(w);
    int j = idx % WW;
    int rem = idx / WW;
    int i = rem % HH;
    int b = rem / HH;
    int lo = i - HALF; if (lo < 0) lo = 0;
    int hi = i + HALF; if (hi > HH - 1) hi = HH - 1;
    const float* base = tmp + (size_t)b * HH * WW + j;
    float acc = 0.0f;
    for (int y = lo; y <= hi; ++y)
        acc += base[(size_t)y * WW] * w[y - i + HALF];
    out[idx] = acc;
}

extern "C" void kernel_launch(void* const* d_in, const int* in_sizes, int n_in,
                              void* d_out, int out_size, void* d_ws, size_t ws_size,
                              hipStream_t stream) {
    // d_in[0] = feature_map (values unused, only shape matters)
    const float* pts = (const float*)d_in[1];
    float* out = (float*)d_out;

    const int PIX = BB * HH * WW;  // 802,816
    float* cnt = (float*)d_ws;     // [B,H,W]
    float* tmp = cnt + PIX;        // [B,H,W]  (needs 2*PIX*4 = 6.4 MB of ws)

    // ws is re-poisoned to 0xAA each call — zero the count grid ourselves.
    hipMemsetAsync(cnt, 0, (size_t)PIX * sizeof(float), stream);

    scatter_counts<<<(BB * NPTS + 255) / 256, 256, 0, stream>>>(pts, cnt);
    hconv<<<(PIX + 255) / 256, 256, 0, stream>>>(cnt, tmp);
    vconv<<<(PIX + 255) / 256, 256, 0, stream>>>(tmp, out);
}

// Round 2
// 243.337 us; speedup vs baseline: 1.1496x; 1.1496x over previous
//
#include <hip/hip_runtime.h>
#include <math.h>

// Problem constants (from reference): feature_map [16,64,224,224], points [16,1024,2]
#define BB   16
#define HH   224
#define WW   224
#define NPTS 1024
#define KS   23      // int(224*0.1)=22 -> +1 = 23
#define HALF 11
#define SIGMA2_2 18.0f  // 2*sigma^2, sigma=3

// L1-normalized 1D gaussian weights. ALL indices compile-time constant after
// full unroll -> w[] stays in VGPRs (lane-varying index would force scratch).
__device__ __forceinline__ void gauss_weights(float* w) {
    float s = 0.0f;
#pragma unroll
    for (int t = 0; t < KS; ++t) {
        float ax = (float)(t - HALF);
        float v = __expf(-(ax * ax) / SIGMA2_2);
        w[t] = v;
        s += v;
    }
    float inv = 1.0f / s;
#pragma unroll
    for (int t = 0; t < KS; ++t) w[t] *= inv;
}

// Scatter point counts into [B,H,W] grid (grid pre-zeroed by memset).
__global__ void scatter_counts(const float* __restrict__ pts, float* __restrict__ cnt) {
    int idx = blockIdx.x * blockDim.x + threadIdx.x;
    if (idx >= BB * NPTS) return;
    int b = idx / NPTS;
    float px = pts[2 * idx + 0];
    float py = pts[2 * idx + 1];
    int x = (int)(px * (float)WW);  // trunc of nonneg == astype(int32)
    int y = (int)(py * (float)HH);
    if ((unsigned)x >= WW || (unsigned)y >= HH) return;
    atomicAdd(&cnt[(b * HH + y) * WW + x], 1.0f);
}

// Horizontal 23-tap conv, zero padding. cnt[B,H,W] -> tmp[B,H,W].
// Fully unrolled: tap index t is compile-time constant -> no scratch.
__global__ void hconv(const float* __restrict__ cnt, float* __restrict__ tmp) {
    int idx = blockIdx.x * blockDim.x + threadIdx.x;
    if (idx >= BB * HH * WW) return;
    float w[KS];
    gauss_weights(w);
    int j = idx % WW;
    int rowbase = idx - j;
    float acc = 0.0f;
#pragma unroll
    for (int t = 0; t < KS; ++t) {
        int x = j + t - HALF;
        float v = ((unsigned)x < (unsigned)WW) ? cnt[rowbase + x] : 0.0f;
        acc = fmaf(v, w[t], acc);
    }
    tmp[idx] = acc;
}

// Vertical 23-tap conv, zero padding. tmp[B,H,W] -> out[B,H,W].
__global__ void vconv(const float* __restrict__ tmp, float* __restrict__ out) {
    int idx = blockIdx.x * blockDim.x + threadIdx.x;
    if (idx >= BB * HH * WW) return;
    float w[KS];
    gauss_weights(w);
    int j = idx % WW;
    int rem = idx / WW;
    int i = rem % HH;
    int b = rem / HH;
    const float* base = tmp + (size_t)b * HH * WW + j;
    float acc = 0.0f;
#pragma unroll
    for (int t = 0; t < KS; ++t) {
        int y = i + t - HALF;
        float v = ((unsigned)y < (unsigned)HH) ? base[(size_t)y * WW] : 0.0f;
        acc = fmaf(v, w[t], acc);
    }
    out[idx] = acc;
}

extern "C" void kernel_launch(void* const* d_in, const int* in_sizes, int n_in,
                              void* d_out, int out_size, void* d_ws, size_t ws_size,
                              hipStream_t stream) {
    // d_in[0] = feature_map (values unused, only shape matters)
    const float* pts = (const float*)d_in[1];
    float* out = (float*)d_out;

    const int PIX = BB * HH * WW;  // 802,816
    float* cnt = (float*)d_ws;     // [B,H,W]
    float* tmp = cnt + PIX;        // [B,H,W]  (2*PIX*4 = 6.4 MB of ws)

    // ws is re-poisoned to 0xAA each call — zero the count grid ourselves.
    hipMemsetAsync(cnt, 0, (size_t)PIX * sizeof(float), stream);

    scatter_counts<<<(BB * NPTS + 255) / 256, 256, 0, stream>>>(pts, cnt);
    hconv<<<(PIX + 255) / 256, 256, 0, stream>>>(cnt, tmp);
    vconv<<<(PIX + 255) / 256, 256, 0, stream>>>(tmp, out);
}